// Round 1
// baseline (339.427 us; speedup 1.0000x reference)
//
#include <hip/hip_runtime.h>
#include <math.h>

#define IN_CAPS 512
#define QN      512
#define IN_DIM  768
#define NCAPS   64
#define DCAPS   16
#define CD      1024   // NCAPS*DCAPS

__device__ __forceinline__ float tanh_fast(float x){
  float e = __expf(2.0f*x);
  return 1.0f - 2.0f/(e+1.0f);
}

__device__ __forceinline__ float wave_max64(float v){
  #pragma unroll
  for (int off=32; off>0; off>>=1) v = fmaxf(v, __shfl_xor(v, off, 64));
  return v;
}
__device__ __forceinline__ float wave_sum64(float v){
  #pragma unroll
  for (int off=32; off>0; off>>=1) v += __shfl_xor(v, off, 64);
  return v;
}

// ---------------- K0: hat = [m;q] @ W_w + W_b  (1024x768 @ 768x1024) ----------------
__global__ __launch_bounds__(256) void gemm_hat(const float* __restrict__ m,
                                                const float* __restrict__ q,
                                                const float* __restrict__ Ww,
                                                const float* __restrict__ Wb,
                                                float* __restrict__ hat)
{
  __shared__ float As[16][65];   // [k][row]  (A transposed)
  __shared__ float Bs[16][65];   // [k][col]
  const int tid = threadIdx.x;
  const int bm = blockIdx.y, bn = blockIdx.x;
  const int tx = tid & 15, ty = tid >> 4;

  float acc[4][4];
  #pragma unroll
  for (int a=0;a<4;a++)
    #pragma unroll
    for (int b=0;b<4;b++) acc[a][b]=0.0f;

  const int r  = tid >> 2;            // 0..63 (row within tile)
  const int kk = (tid & 3) << 2;      // 0,4,8,12
  const int row = bm*64 + r;
  const float* srcA = (row < IN_CAPS) ? (m + row*IN_DIM) : (q + (row-IN_CAPS)*IN_DIM);
  const int krow = tid >> 4;          // 0..15
  const int cc   = (tid & 15) << 2;   // 0..60

  for (int k0=0; k0<IN_DIM; k0+=16){
    float4 av = *(const float4*)(srcA + k0 + kk);
    As[kk+0][r]=av.x; As[kk+1][r]=av.y; As[kk+2][r]=av.z; As[kk+3][r]=av.w;
    float4 bv = *(const float4*)(Ww + (size_t)(k0+krow)*CD + bn*64 + cc);
    Bs[krow][cc+0]=bv.x; Bs[krow][cc+1]=bv.y; Bs[krow][cc+2]=bv.z; Bs[krow][cc+3]=bv.w;
    __syncthreads();
    #pragma unroll
    for (int k=0;k<16;k++){
      float a[4], b[4];
      #pragma unroll
      for (int j=0;j<4;j++) a[j] = As[k][ty*4+j];
      #pragma unroll
      for (int j=0;j<4;j++) b[j] = Bs[k][tx*4+j];
      #pragma unroll
      for (int ii=0;ii<4;ii++)
        #pragma unroll
        for (int jj=0;jj<4;jj++) acc[ii][jj] += a[ii]*b[jj];
    }
    __syncthreads();
  }
  #pragma unroll
  for (int ii=0;ii<4;ii++){
    const int orow = bm*64 + ty*4 + ii;
    #pragma unroll
    for (int jj=0;jj<4;jj++){
      const int ocol = bn*64 + tx*4 + jj;
      hat[(size_t)orow*CD + ocol] = acc[ii][jj] + Wb[ocol];
    }
  }
}

// ---------------- K1: per-(i,c) variance of centered m + transposed copy ----------------
// mT[i][d][c] = hat_m[i][c][d]   (so routing loads with lane=c are coalesced)
__global__ __launch_bounds__(256) void stats_kernel(const float* __restrict__ hat,
                                                    float* __restrict__ mT,
                                                    float* __restrict__ nm2)
{
  const int t = blockIdx.x*256 + threadIdx.x;    // 0..32767
  const int i = t >> 6, c = t & 63;
  const float* row = hat + (size_t)i*CD + c*16;
  float v[16]; float s=0.f;
  #pragma unroll
  for (int d=0;d<16;d++){ v[d]=row[d]; s+=v[d]; }
  const float mean = s*(1.0f/16.0f);
  float n2=0.f;
  #pragma unroll
  for (int d=0;d<16;d++){ float x=v[d]-mean; n2+=x*x; }
  nm2[i*64+c] = n2;
  #pragma unroll
  for (int d=0;d<16;d++) mT[(size_t)i*CD + d*64 + c] = v[d];
}

// ---------------- K2: routing, one q per block ----------------
__global__ __launch_bounds__(256) void routing_kernel(const float* __restrict__ hat,
                                                      const float* __restrict__ mT,
                                                      const float* __restrict__ nm2g,
                                                      float* __restrict__ out)
{
  __shared__ float red[4][64][17];
  const int qidx = blockIdx.x;
  const int tid = threadIdx.x;
  const int w = tid >> 6;       // wave 0..3
  const int c = tid & 63;       // lane = capsule

  // q_cur (= hat_q row), per lane c holds the 16-dim capsule vector
  float qc[16];
  {
    const float* hq = hat + (size_t)(IN_CAPS + qidx)*CD + c*16;
    #pragma unroll
    for (int d=0;d<16;d++) qc[d] = hq[d];
  }

  float qcc1[16], qcc2[16];
  float nq2_1, nq2_2, nq2_3;
  {
    float s=0.f;
    #pragma unroll
    for (int d=0;d<16;d++) s += qc[d];
    const float mean = s*(1.0f/16.0f);
    float n2=0.f;
    #pragma unroll
    for (int d=0;d<16;d++){ qcc1[d]=qc[d]-mean; n2 += qcc1[d]*qcc1[d]; }
    nq2_1 = n2;
  }

  float v1[16], v2[16], acc[16];
  const int i0 = w*128, i1 = i0+128;

  // ======== pass 1:  hat_v1 = sum_i (1/64 + p1) * m ========
  #pragma unroll
  for (int d=0;d<16;d++) acc[d]=0.f;
  for (int i=i0;i<i1;i++){
    float mr[16];
    const float* mrow = mT + (size_t)i*CD + c;
    #pragma unroll
    for (int d=0;d<16;d++) mr[d] = mrow[d*64];
    const float nm2i = nm2g[i*64 + c];
    float num=0.f;
    #pragma unroll
    for (int d=0;d<16;d++) num += mr[d]*qcc1[d];
    const float p1 = tanh_fast(num * __frsqrt_rn(nm2i*nq2_1 + 1e-8f));
    const float wgt = 0.015625f + p1;   // softmax(0) = 1/64 exactly
    #pragma unroll
    for (int d=0;d<16;d++) acc[d] += wgt*mr[d];
  }
  // reduce across waves -> hat_v1 -> squash -> v1
  {
    #pragma unroll
    for (int d=0;d<16;d++) red[w][c][d] = acc[d];
    __syncthreads();
    float n2=0.f;
    #pragma unroll
    for (int d=0;d<16;d++){
      const float hv = red[0][c][d]+red[1][c][d]+red[2][c][d]+red[3][c][d];
      v1[d]=hv; n2 += hv*hv;
    }
    __syncthreads();
    const float sc = n2 / ((1.0f+n2)*sqrtf(n2+1e-8f));
    #pragma unroll
    for (int d=0;d<16;d++) v1[d] *= sc;
  }
  // q_cur2 = (q_cur1 + v1)/2 -> qcc2
  {
    float s=0.f;
    #pragma unroll
    for (int d=0;d<16;d++){ qc[d] = 0.5f*(qc[d]+v1[d]); s += qc[d]; }
    const float mean = s*(1.0f/16.0f);
    float n2=0.f;
    #pragma unroll
    for (int d=0;d<16;d++){ qcc2[d]=qc[d]-mean; n2+=qcc2[d]*qcc2[d]; }
    nq2_2 = n2;
  }

  // ======== pass 2:  hat_v2 = sum_i (softmax_c(p1*cos1) + p2) * m ========
  #pragma unroll
  for (int d=0;d<16;d++) acc[d]=0.f;
  for (int i=i0;i<i1;i++){
    float mr[16];
    const float* mrow = mT + (size_t)i*CD + c;
    #pragma unroll
    for (int d=0;d<16;d++) mr[d] = mrow[d*64];
    const float nm2i = nm2g[i*64 + c];
    float n1=0.f, cv1=0.f, n2d=0.f;
    #pragma unroll
    for (int d=0;d<16;d++){
      n1  += mr[d]*qcc1[d];
      cv1 += mr[d]*v1[d];
      n2d += mr[d]*qcc2[d];
    }
    const float p1 = tanh_fast(n1  * __frsqrt_rn(nm2i*nq2_1 + 1e-8f));
    const float p2 = tanh_fast(n2d * __frsqrt_rn(nm2i*nq2_2 + 1e-8f));
    const float a1 = p1*cv1;
    const float mx = wave_max64(a1);
    const float e  = __expf(a1 - mx);
    const float ssum = wave_sum64(e);
    const float d2 = e / ssum;
    const float wgt = d2 + p2;
    #pragma unroll
    for (int d=0;d<16;d++) acc[d] += wgt*mr[d];
  }
  {
    #pragma unroll
    for (int d=0;d<16;d++) red[w][c][d] = acc[d];
    __syncthreads();
    float n2=0.f;
    #pragma unroll
    for (int d=0;d<16;d++){
      const float hv = red[0][c][d]+red[1][c][d]+red[2][c][d]+red[3][c][d];
      v2[d]=hv; n2 += hv*hv;
    }
    __syncthreads();
    const float sc = n2 / ((1.0f+n2)*sqrtf(n2+1e-8f));
    #pragma unroll
    for (int d=0;d<16;d++) v2[d] *= sc;
  }
  // q_cur3 = (q_cur2 + v2)/2 -> qcc3 (in place in qc)
  {
    float s=0.f;
    #pragma unroll
    for (int d=0;d<16;d++){ qc[d] = 0.5f*(qc[d]+v2[d]); s += qc[d]; }
    const float mean = s*(1.0f/16.0f);
    float n2=0.f;
    #pragma unroll
    for (int d=0;d<16;d++){ qc[d]-=mean; n2+=qc[d]*qc[d]; }
    nq2_3 = n2;
  }

  // ======== pass 3:  out = squash( sum_i (softmax_c(p1*cos1+p2*cos2) + p3) * m ) ========
  #pragma unroll
  for (int d=0;d<16;d++) acc[d]=0.f;
  for (int i=i0;i<i1;i++){
    float mr[16];
    const float* mrow = mT + (size_t)i*CD + c;
    #pragma unroll
    for (int d=0;d<16;d++) mr[d] = mrow[d*64];
    const float nm2i = nm2g[i*64 + c];
    float n1=0.f, cv1=0.f, n2d=0.f, cv2=0.f, n3=0.f;
    #pragma unroll
    for (int d=0;d<16;d++){
      n1  += mr[d]*qcc1[d];
      cv1 += mr[d]*v1[d];
      n2d += mr[d]*qcc2[d];
      cv2 += mr[d]*v2[d];
      n3  += mr[d]*qc[d];       // qc holds qcc3
    }
    const float p1 = tanh_fast(n1  * __frsqrt_rn(nm2i*nq2_1 + 1e-8f));
    const float p2 = tanh_fast(n2d * __frsqrt_rn(nm2i*nq2_2 + 1e-8f));
    const float p3 = tanh_fast(n3  * __frsqrt_rn(nm2i*nq2_3 + 1e-8f));
    const float a2v = p1*cv1 + p2*cv2;
    const float mx = wave_max64(a2v);
    const float e  = __expf(a2v - mx);
    const float ssum = wave_sum64(e);
    const float d3 = e / ssum;
    const float wgt = d3 + p3;
    #pragma unroll
    for (int d=0;d<16;d++) acc[d] += wgt*mr[d];
  }
  {
    #pragma unroll
    for (int d=0;d<16;d++) red[w][c][d] = acc[d];
    __syncthreads();
    if (w==0){
      float hv[16]; float n2=0.f;
      #pragma unroll
      for (int d=0;d<16;d++){
        hv[d] = red[0][c][d]+red[1][c][d]+red[2][c][d]+red[3][c][d];
        n2 += hv[d]*hv[d];
      }
      const float sc = n2 / ((1.0f+n2)*sqrtf(n2+1e-8f));
      float* op = out + (size_t)qidx*CD + c*16;
      #pragma unroll
      for (int d=0;d<16;d++) op[d] = hv[d]*sc;
    }
  }
}

extern "C" void kernel_launch(void* const* d_in, const int* in_sizes, int n_in,
                              void* d_out, int out_size, void* d_ws, size_t ws_size,
                              hipStream_t stream)
{
  const float* m  = (const float*)d_in[0];
  const float* q  = (const float*)d_in[1];
  const float* Ww = (const float*)d_in[2];
  const float* Wb = (const float*)d_in[3];
  float* out = (float*)d_out;

  float* hat  = (float*)d_ws;                 // 1024*1024 floats (rows 0..511 = hat_m, 512..1023 = hat_q)
  float* mT   = hat + (size_t)1024*1024;      // 512*1024 floats, transposed hat_m
  float* nm2  = mT  + (size_t)512*1024;       // 512*64 floats

  dim3 g0(16,16);
  gemm_hat<<<g0, 256, 0, stream>>>(m, q, Ww, Wb, hat);
  stats_kernel<<<128, 256, 0, stream>>>(hat, mT, nm2);
  routing_kernel<<<512, 256, 0, stream>>>(hat, mT, nm2, out);
}

// Round 2
// 265.394 us; speedup vs baseline: 1.2790x; 1.2790x over previous
//
#include <hip/hip_runtime.h>
#include <math.h>

#define IN_CAPS 512
#define QN      512
#define IN_DIM  768
#define NCAPS   64
#define DCAPS   16
#define CD      1024   // NCAPS*DCAPS

__device__ __forceinline__ float tanh_fast(float x){
  float e = __expf(2.0f*x);
  return 1.0f - 2.0f/(e+1.0f);
}

__device__ __forceinline__ float wave_sum64(float v){
  #pragma unroll
  for (int off=32; off>0; off>>=1) v += __shfl_xor(v, off, 64);
  return v;
}

#define LD16(dst, ptr) { const float4* _p=(const float4*)(ptr); \
  float4 _a=_p[0], _b=_p[1], _c=_p[2], _d=_p[3]; \
  dst[0]=_a.x; dst[1]=_a.y; dst[2]=_a.z; dst[3]=_a.w; \
  dst[4]=_b.x; dst[5]=_b.y; dst[6]=_b.z; dst[7]=_b.w; \
  dst[8]=_c.x; dst[9]=_c.y; dst[10]=_c.z; dst[11]=_c.w; \
  dst[12]=_d.x; dst[13]=_d.y; dst[14]=_d.z; dst[15]=_d.w; }

// ---------------- K0: hat = [m;q] @ W_w + W_b  (1024x768 @ 768x1024) ----------------
__global__ __launch_bounds__(256) void gemm_hat(const float* __restrict__ m,
                                                const float* __restrict__ q,
                                                const float* __restrict__ Ww,
                                                const float* __restrict__ Wb,
                                                float* __restrict__ hat)
{
  __shared__ float As[16][65];   // [k][row]  (A transposed)
  __shared__ float Bs[16][65];   // [k][col]
  const int tid = threadIdx.x;
  const int bm = blockIdx.y, bn = blockIdx.x;
  const int tx = tid & 15, ty = tid >> 4;

  float acc[4][4];
  #pragma unroll
  for (int a=0;a<4;a++)
    #pragma unroll
    for (int b=0;b<4;b++) acc[a][b]=0.0f;

  const int r  = tid >> 2;            // 0..63 (row within tile)
  const int kk = (tid & 3) << 2;      // 0,4,8,12
  const int row = bm*64 + r;
  const float* srcA = (row < IN_CAPS) ? (m + row*IN_DIM) : (q + (row-IN_CAPS)*IN_DIM);
  const int krow = tid >> 4;          // 0..15
  const int cc   = (tid & 15) << 2;   // 0..60

  for (int k0=0; k0<IN_DIM; k0+=16){
    float4 av = *(const float4*)(srcA + k0 + kk);
    As[kk+0][r]=av.x; As[kk+1][r]=av.y; As[kk+2][r]=av.z; As[kk+3][r]=av.w;
    float4 bv = *(const float4*)(Ww + (size_t)(k0+krow)*CD + bn*64 + cc);
    Bs[krow][cc+0]=bv.x; Bs[krow][cc+1]=bv.y; Bs[krow][cc+2]=bv.z; Bs[krow][cc+3]=bv.w;
    __syncthreads();
    #pragma unroll
    for (int k=0;k<16;k++){
      float a[4], b[4];
      #pragma unroll
      for (int j=0;j<4;j++) a[j] = As[k][ty*4+j];
      #pragma unroll
      for (int j=0;j<4;j++) b[j] = Bs[k][tx*4+j];
      #pragma unroll
      for (int ii=0;ii<4;ii++)
        #pragma unroll
        for (int jj=0;jj<4;jj++) acc[ii][jj] += a[ii]*b[jj];
    }
    __syncthreads();
  }
  #pragma unroll
  for (int ii=0;ii<4;ii++){
    const int orow = bm*64 + ty*4 + ii;
    #pragma unroll
    for (int jj=0;jj<4;jj++){
      const int ocol = bn*64 + tx*4 + jj;
      hat[(size_t)orow*CD + ocol] = acc[ii][jj] + Wb[ocol];
    }
  }
}

// ---------------- K1: per-(i,c) stats:  rnm = rsqrt(||m-mean||^2),  sm = sum_d m ----------------
__global__ __launch_bounds__(256) void stats_kernel(const float* __restrict__ hat,
                                                    float* __restrict__ rnm,
                                                    float* __restrict__ sm)
{
  const int t = blockIdx.x*256 + threadIdx.x;    // 0..32767
  const int i = t >> 6, c = t & 63;
  float v[16];
  LD16(v, hat + (size_t)i*CD + c*16);
  float s=0.f;
  #pragma unroll
  for (int d=0;d<16;d++) s += v[d];
  const float mean = s*(1.0f/16.0f);
  float n2=0.f;
  #pragma unroll
  for (int d=0;d<16;d++){ float x=v[d]-mean; n2+=x*x; }
  rnm[t] = __frsqrt_rn(n2 + 1e-12f);
  sm[t]  = s;
}

// ---------------- K2: routing, one q per block, 8 waves ----------------
__global__ __launch_bounds__(512, 4) void routing_kernel(const float* __restrict__ hat,
                                                         const float* __restrict__ rnm_g,
                                                         const float* __restrict__ sm_g,
                                                         float* __restrict__ out)
{
  __shared__ float red[8][64][17];
  __shared__ float hvl[64][17];
  const int qidx = blockIdx.x;
  const int tid = threadIdx.x;
  const int w = tid >> 6;       // wave 0..7
  const int c = tid & 63;       // lane = capsule

  // q_cur (= hat_q row), per lane c holds the 16-dim capsule vector
  float qc[16];
  LD16(qc, hat + (size_t)(IN_CAPS + qidx)*CD + c*16);

  float qcc1[16];
  float s1, s2, s3;             // rsqrt(nq2_x)
  {
    float s=0.f;
    #pragma unroll
    for (int d=0;d<16;d++) s += qc[d];
    const float mean = s*(1.0f/16.0f);
    float n2=0.f;
    #pragma unroll
    for (int d=0;d<16;d++){ qcc1[d]=qc[d]-mean; n2 += qcc1[d]*qcc1[d]; }
    s1 = __frsqrt_rn(n2 + 1e-12f);
  }

  float v1[16], v2[16], acc[16];
  const int i0 = w*64, i1 = i0+64;

  // ======== pass 1:  hat_v1 = sum_i (1/64 + p1) * m ========
  #pragma unroll
  for (int d=0;d<16;d++) acc[d]=0.f;
  for (int i=i0;i<i1;i++){
    float mr[16];
    LD16(mr, hat + (size_t)i*CD + c*16);
    const float rnm = rnm_g[i*64 + c];
    float n1=0.f;
    #pragma unroll
    for (int d=0;d<16;d++) n1 += mr[d]*qcc1[d];
    const float p1 = tanh_fast(n1*rnm*s1);
    const float wgt = 0.015625f + p1;   // softmax(0) = 1/64 exactly
    #pragma unroll
    for (int d=0;d<16;d++) acc[d] += wgt*mr[d];
  }
  // reduce across 8 waves -> hat_v1 -> squash -> v1
  {
    #pragma unroll
    for (int d=0;d<16;d++) red[w][c][d] = acc[d];
    __syncthreads();
    for (int e=tid; e<1024; e+=512){
      const int cc = e>>4, dd = e&15;
      float s = red[0][cc][dd]+red[1][cc][dd]+red[2][cc][dd]+red[3][cc][dd]
              + red[4][cc][dd]+red[5][cc][dd]+red[6][cc][dd]+red[7][cc][dd];
      hvl[cc][dd] = s;
    }
    __syncthreads();
    float n2=0.f;
    #pragma unroll
    for (int d=0;d<16;d++){ v1[d]=hvl[c][d]; n2 += v1[d]*v1[d]; }
    const float sc = n2 / ((1.0f+n2)*sqrtf(n2+1e-8f));
    #pragma unroll
    for (int d=0;d<16;d++) v1[d] *= sc;
  }
  // q_cur2 = (q_cur1 + v1)/2 ; nq2_2 via sum/sumsq; mv1 = mean(v1)
  float mv1, mv2;
  {
    float sv=0.f;
    #pragma unroll
    for (int d=0;d<16;d++) sv += v1[d];
    mv1 = sv*(1.0f/16.0f);
    float s=0.f, ss=0.f;
    #pragma unroll
    for (int d=0;d<16;d++){ qc[d] = 0.5f*(qc[d]+v1[d]); s += qc[d]; ss += qc[d]*qc[d]; }
    const float mean = s*(1.0f/16.0f);
    const float n2 = ss - 16.0f*mean*mean;
    s2 = __frsqrt_rn(n2 + 1e-12f);
  }

  // ======== pass 2:  hat_v2 = sum_i (softmax_c(p1*cv1) + p2) * m ========
  #pragma unroll
  for (int d=0;d<16;d++) acc[d]=0.f;
  for (int i=i0;i<i1;i++){
    float mr[16];
    LD16(mr, hat + (size_t)i*CD + c*16);
    const float rnm = rnm_g[i*64 + c];
    const float smi = sm_g[i*64 + c];
    float n1=0.f, cv1=0.f;
    #pragma unroll
    for (int d=0;d<16;d++){ n1 += mr[d]*qcc1[d]; cv1 += mr[d]*v1[d]; }
    const float p1 = tanh_fast(n1*rnm*s1);
    const float n2d = 0.5f*(n1 + cv1 - mv1*smi);
    const float p2 = tanh_fast(n2d*rnm*s2);
    const float e  = __expf(p1*cv1);             // logits bounded, no max needed
    const float ssum = wave_sum64(e);
    const float wgt = e*__frcp_rn(ssum) + p2;
    #pragma unroll
    for (int d=0;d<16;d++) acc[d] += wgt*mr[d];
  }
  {
    #pragma unroll
    for (int d=0;d<16;d++) red[w][c][d] = acc[d];
    __syncthreads();
    for (int e=tid; e<1024; e+=512){
      const int cc = e>>4, dd = e&15;
      float s = red[0][cc][dd]+red[1][cc][dd]+red[2][cc][dd]+red[3][cc][dd]
              + red[4][cc][dd]+red[5][cc][dd]+red[6][cc][dd]+red[7][cc][dd];
      hvl[cc][dd] = s;
    }
    __syncthreads();
    float n2=0.f;
    #pragma unroll
    for (int d=0;d<16;d++){ v2[d]=hvl[c][d]; n2 += v2[d]*v2[d]; }
    const float sc = n2 / ((1.0f+n2)*sqrtf(n2+1e-8f));
    #pragma unroll
    for (int d=0;d<16;d++) v2[d] *= sc;
  }
  // q_cur3 = (q_cur2 + v2)/2 ; nq2_3 ; mv2 = mean(v2)
  {
    float sv=0.f;
    #pragma unroll
    for (int d=0;d<16;d++) sv += v2[d];
    mv2 = sv*(1.0f/16.0f);
    float s=0.f, ss=0.f;
    #pragma unroll
    for (int d=0;d<16;d++){ qc[d] = 0.5f*(qc[d]+v2[d]); s += qc[d]; ss += qc[d]*qc[d]; }
    const float mean = s*(1.0f/16.0f);
    const float n2 = ss - 16.0f*mean*mean;
    s3 = __frsqrt_rn(n2 + 1e-12f);
  }

  // ======== pass 3:  out = squash( sum_i (softmax_c(p1*cv1+p2*cv2) + p3) * m ) ========
  #pragma unroll
  for (int d=0;d<16;d++) acc[d]=0.f;
  for (int i=i0;i<i1;i++){
    float mr[16];
    LD16(mr, hat + (size_t)i*CD + c*16);
    const float rnm = rnm_g[i*64 + c];
    const float smi = sm_g[i*64 + c];
    float n1=0.f, cv1=0.f, cv2=0.f;
    #pragma unroll
    for (int d=0;d<16;d++){
      n1  += mr[d]*qcc1[d];
      cv1 += mr[d]*v1[d];
      cv2 += mr[d]*v2[d];
    }
    const float p1 = tanh_fast(n1*rnm*s1);
    const float n2d = 0.5f*(n1 + cv1 - mv1*smi);
    const float p2 = tanh_fast(n2d*rnm*s2);
    const float n3 = 0.5f*(n2d + cv2 - mv2*smi);
    const float p3 = tanh_fast(n3*rnm*s3);
    const float e  = __expf(p1*cv1 + p2*cv2);
    const float ssum = wave_sum64(e);
    const float wgt = e*__frcp_rn(ssum) + p3;
    #pragma unroll
    for (int d=0;d<16;d++) acc[d] += wgt*mr[d];
  }
  {
    #pragma unroll
    for (int d=0;d<16;d++) red[w][c][d] = acc[d];
    __syncthreads();
    for (int e=tid; e<1024; e+=512){
      const int cc = e>>4, dd = e&15;
      float s = red[0][cc][dd]+red[1][cc][dd]+red[2][cc][dd]+red[3][cc][dd]
              + red[4][cc][dd]+red[5][cc][dd]+red[6][cc][dd]+red[7][cc][dd];
      hvl[cc][dd] = s;
    }
    __syncthreads();
    if (w==0){
      float hv[16]; float n2=0.f;
      #pragma unroll
      for (int d=0;d<16;d++){ hv[d]=hvl[c][d]; n2 += hv[d]*hv[d]; }
      const float sc = n2 / ((1.0f+n2)*sqrtf(n2+1e-8f));
      float4* op = (float4*)(out + (size_t)qidx*CD + c*16);
      float o[16];
      #pragma unroll
      for (int d=0;d<16;d++) o[d] = hv[d]*sc;
      op[0] = make_float4(o[0],o[1],o[2],o[3]);
      op[1] = make_float4(o[4],o[5],o[6],o[7]);
      op[2] = make_float4(o[8],o[9],o[10],o[11]);
      op[3] = make_float4(o[12],o[13],o[14],o[15]);
    }
  }
}

extern "C" void kernel_launch(void* const* d_in, const int* in_sizes, int n_in,
                              void* d_out, int out_size, void* d_ws, size_t ws_size,
                              hipStream_t stream)
{
  const float* m  = (const float*)d_in[0];
  const float* q  = (const float*)d_in[1];
  const float* Ww = (const float*)d_in[2];
  const float* Wb = (const float*)d_in[3];
  float* out = (float*)d_out;

  float* hat  = (float*)d_ws;                 // 1024*1024 floats (rows 0..511 = hat_m, 512..1023 = hat_q)
  float* rnm  = hat + (size_t)1024*1024;      // 512*64
  float* sm   = rnm + (size_t)512*64;         // 512*64

  dim3 g0(16,16);
  gemm_hat<<<g0, 256, 0, stream>>>(m, q, Ww, Wb, hat);
  stats_kernel<<<128, 256, 0, stream>>>(hat, rnm, sm);
  routing_kernel<<<512, 512, 0, stream>>>(hat, rnm, sm, out);
}